// Round 10
// baseline (360.854 us; speedup 1.0000x reference)
//
#include <hip/hip_runtime.h>
#include <hip/hip_bf16.h>

// ---------------------------------------------------------------------------
// HybridGATLSTM on MI355X — round 16.
//   r15 (fused 190us, total 353) = specialized proj/rec pipeline. Occupancy
//   integral shows GAT drains in ~50us; the rest is pure LSTM tail. Residuals
//   attacked here, all bit-exact:
//     (1) L0 deferred-flag publish: chunk atomics issued post-barrier, the
//         NEXT step's end-barrier drains them (vmcnt piggyback), flag one
//         step later. Removes ~10us of serial publish stalls from L0.
//     (2) s_sleep(16)->s_sleep(2) in all spins (1024->128cyc discovery);
//         setprio(1) in proj blocks (inter-layer critical path).
//     (3) Heads merged into ONE kernel (atomic counter, last block runs the
//         final stage; threadfence release/acquire, r14/r15-proven).
//   absmax must stay exactly 0.0001220703.
//   GAT body r11 verbatim; proj/rec/L0 otherwise r15 verbatim.
// ---------------------------------------------------------------------------

typedef _Float16 half8 __attribute__((ext_vector_type(8)));
typedef float floatx4 __attribute__((ext_vector_type(4)));
typedef float float4v __attribute__((ext_vector_type(4)));

#define LOG2E 1.44269504088896f

__device__ __forceinline__ float fast_exp(float x) {
    return __builtin_amdgcn_exp2f(x * LOG2E);
}
__device__ __forceinline__ float sigm(float x) {
    x = fminf(fmaxf(x, -30.f), 30.f);
    return __builtin_amdgcn_rcpf(1.f + __builtin_amdgcn_exp2f(-x * LOG2E));
}
__device__ __forceinline__ float tanhp(float x) {
    x = fminf(fmaxf(x, -15.f), 15.f);
    float e = __builtin_amdgcn_exp2f(-2.f * LOG2E * x);
    return (1.f - e) * __builtin_amdgcn_rcpf(1.f + e);
}
__device__ __forceinline__ void split8v(float4v v0, float4v v1, half8& hi, half8& lo) {
#pragma unroll
    for (int j = 0; j < 4; ++j) {
        _Float16 h = (_Float16)v0[j];
        hi[j] = h; lo[j] = (_Float16)(v0[j] - (float)h);
    }
#pragma unroll
    for (int j = 0; j < 4; ++j) {
        _Float16 h = (_Float16)v1[j];
        hi[4 + j] = h; lo[4 + j] = (_Float16)(v1[j] - (float)h);
    }
}

// ---------------------------------------------------------------------------
// Shared-memory layouts (union'd). LstmSh 21.3KB, GatSh ~34.5KB -> union 35KB.
// ---------------------------------------------------------------------------
struct LstmSh {
    float hbuf[2][544];       // 2 buffers x 4 bank-shifted copies(136)
    float stage[2][16 * 132]; // ping-pong h-chunk staging
};
struct GatSh {
    unsigned long long adjm[256];
    float xv[128];
    float u1[32], v1[32], coef[4];
    float s1v[128];
    float h2s[128 * 33];
    float wh2[128 * 17];
    float Lv[128], Rv[128], rd2[128];
    float d_h[4][128], s_h[4][128];
};
union ShU { LstmSh l; GatSh g; };

// ---------------------------------------------------------------------------
// L0 block: full proj upfront (private Pre0), 96 straight rec steps,
// DEFERRED-FLAG chunk publish: atomics post-barrier of step 16k+15; flag
// post-barrier of step 16k+16 (that barrier drains each thread's atomics).
// ---------------------------------------------------------------------------
__device__ __forceinline__ void l0_body(LstmSh& sh, int b,
    const float* __restrict__ x, const float* __restrict__ Wih,
    const float* __restrict__ Whh, const float* __restrict__ bih,
    const float* __restrict__ bhh,
    float* __restrict__ Pre0,        // [96*512], private to this block
    float* __restrict__ Hout,        // [96][128] (atomic-published)
    int* __restrict__ fHout)         // 6 chunk flags
{
    int tid = threadIdx.x;
    int w = tid >> 6, lane = tid & 63, quad = lane >> 4, sub = lane & 15;
    int hu = 16 * w + sub, c4 = quad;

    __builtin_amdgcn_s_setprio(1);
    // ---- full proj (r11 verbatim, layer 0)
    {
        half8 bhi[4][4], blo[4][4];
        float bias[4];
#pragma unroll
        for (int tt = 0; tt < 4; ++tt) {
            int r = tt * 128 + 16 * w + sub;
            bias[tt] = bih[r] + bhh[r];
#pragma unroll
            for (int kc = 0; kc < 4; ++kc) {
                const float4v* p = (const float4v*)(Wih + r * 128 + kc * 32 + quad * 8);
                split8v(p[0], p[1], bhi[tt][kc], blo[tt][kc]);
            }
        }
        for (int mt = 0; mt < 6; ++mt) {
            half8 ahi[4], alo[4];
            const float* arow = x + b * 12288 + (mt * 16 + sub) * 128;
#pragma unroll
            for (int kc = 0; kc < 4; ++kc) {
                const float4v* p = (const float4v*)(arow + kc * 32 + quad * 8);
                split8v(p[0], p[1], ahi[kc], alo[kc]);
            }
            floatx4 acc[4];
#pragma unroll
            for (int tt = 0; tt < 4; ++tt) {
                floatx4 a = {bias[tt], bias[tt], bias[tt], bias[tt]};
                acc[tt] = a;
            }
#pragma unroll
            for (int tt = 0; tt < 4; ++tt)
#pragma unroll
                for (int kc = 0; kc < 4; ++kc) {
                    acc[tt] = __builtin_amdgcn_mfma_f32_16x16x32_f16(ahi[kc], bhi[tt][kc], acc[tt], 0, 0, 0);
                    acc[tt] = __builtin_amdgcn_mfma_f32_16x16x32_f16(ahi[kc], blo[tt][kc], acc[tt], 0, 0, 0);
                    acc[tt] = __builtin_amdgcn_mfma_f32_16x16x32_f16(alo[kc], bhi[tt][kc], acc[tt], 0, 0, 0);
                }
#pragma unroll
            for (int tt = 0; tt < 4; ++tt)
#pragma unroll
                for (int reg = 0; reg < 4; ++reg)
                    Pre0[(mt * 16 + quad * 4 + reg) * 512 + tt * 128 + 16 * w + sub] = acc[tt][reg];
        }
    }
    // ---- rec: weights resident, 96 steps (r11 verbatim) + deferred publish
    float4v wgt[4][8];
#pragma unroll
    for (int g = 0; g < 4; ++g) {
        const float4v* p = (const float4v*)(Whh + (g * 128 + hu) * 128 + c4 * 32);
#pragma unroll
        for (int k = 0; k < 8; ++k) wgt[g][k] = p[k];
    }
    sh.hbuf[0][c4 * 136 + hu] = 0.f;
    float cvar = 0.f;
    __syncthreads();

    for (int t = 0; t < 96; ++t) {
        int rb = t & 1, wb = rb ^ 1;
        float pre[4];
#pragma unroll
        for (int g = 0; g < 4; ++g)
            pre[g] = Pre0[t * 512 + g * 128 + hu];
        const float4v* hc = (const float4v*)(&sh.hbuf[rb][c4 * 168]);
        float4v p4[4];
#pragma unroll
        for (int g = 0; g < 4; ++g) { float4v z = {0.f,0.f,0.f,0.f}; p4[g] = z; }
#pragma unroll
        for (int k = 0; k < 8; ++k) {
            float4v hv = hc[k];
#pragma unroll
            for (int g = 0; g < 4; ++g) p4[g] += wgt[g][k] * hv;
        }
        float p[4];
#pragma unroll
        for (int g = 0; g < 4; ++g) {
            float s = p4[g].x + p4[g].y + p4[g].z + p4[g].w;
            s += __shfl_xor(s, 16, 64);
            s += __shfl_xor(s, 32, 64);
            p[g] = s + pre[g];
        }
        float c = sigm(p[1]) * cvar + sigm(p[0]) * tanhp(p[2]);
        cvar = c;
        float h = sigm(p[3]) * tanhp(c);
        sh.hbuf[wb][c4 * 136 + hu] = h;
        if (c4 == 0) sh.stage[(t >> 4) & 1][(t & 15) * 132 + hu] = h;
        __syncthreads();
        // ---- post-barrier region of step t:
        if ((t & 15) == 15) {
            // issue chunk-k publish atomics; NEXT step's barrier drains them
            int k = t >> 4;
            float* outp = Hout + k * 2048;
            const float* st = sh.stage[k & 1];
#pragma unroll
            for (int u = 0; u < 4; ++u) {
                int e = tid * 4 + u;
                atomicExch(&outp[e], st[(e >> 7) * 132 + (e & 127)]);
            }
        } else if ((t & 15) == 0 && t >= 16 && tid == 0) {
            // flag for chunk (t>>4)-1: its atomics were drained by the
            // barrier of step t (each thread waits its own vmcnt there).
            atomicExch(&fHout[(t >> 4) - 1], 1);
        }
    }
    __syncthreads();   // drain chunk-5 atomics (issued post step 95)
    if (tid == 0) atomicExch(&fHout[5], 1);
    __builtin_amdgcn_s_setprio(0);
}

// ---------------------------------------------------------------------------
// Proj block (layers 1,2): Wih B-frags resident across all chunks.
// ---------------------------------------------------------------------------
__device__ __forceinline__ void proj_body(LstmSh& sh, int layer,
    const float* __restrict__ Wih, const float* __restrict__ bih,
    const float* __restrict__ bhh,
    const float* __restrict__ Hin, int* __restrict__ fH,
    float* __restrict__ PreRing, int* __restrict__ fP,
    int* __restrict__ cons)
{
    int tid = threadIdx.x;
    int w = tid >> 6, lane = tid & 63, quad = lane >> 4, sub = lane & 15;
    const float* WihL = Wih + layer * 65536;

    __builtin_amdgcn_s_setprio(1);   // inter-layer critical path
    half8 bhi[4][4], blo[4][4];
    float bias[4];
#pragma unroll
    for (int tt = 0; tt < 4; ++tt) {
        int r = tt * 128 + 16 * w + sub;
        bias[tt] = bih[layer * 512 + r] + bhh[layer * 512 + r];
#pragma unroll
        for (int kc = 0; kc < 4; ++kc) {
            const float4v* p = (const float4v*)(WihL + r * 128 + kc * 32 + quad * 8);
            split8v(p[0], p[1], bhi[tt][kc], blo[tt][kc]);
        }
    }
    for (int k = 0; k < 6; ++k) {
        if (tid == 0) {
            while (atomicAdd(&fH[k], 0) == 0) __builtin_amdgcn_s_sleep(2);
        }
        __syncthreads();
        {
            const float* inp = Hin + k * 2048;
#pragma unroll
            for (int u = 0; u < 4; ++u) {
                int e = tid * 4 + u;
                sh.stage[0][(e >> 7) * 132 + (e & 127)] =
                    atomicAdd((float*)&inp[e], 0.f);
            }
        }
        __syncthreads();
        half8 ahi[4], alo[4];
        const float* arow = &sh.stage[0][sub * 132];
#pragma unroll
        for (int kc = 0; kc < 4; ++kc) {
            const float4v* p = (const float4v*)(arow + kc * 32 + quad * 8);
            split8v(p[0], p[1], ahi[kc], alo[kc]);
        }
        floatx4 acc[4];
#pragma unroll
        for (int tt = 0; tt < 4; ++tt) {
            floatx4 a = {bias[tt], bias[tt], bias[tt], bias[tt]};
            acc[tt] = a;
        }
#pragma unroll
        for (int tt = 0; tt < 4; ++tt)
#pragma unroll
            for (int kc = 0; kc < 4; ++kc) {
                acc[tt] = __builtin_amdgcn_mfma_f32_16x16x32_f16(ahi[kc], bhi[tt][kc], acc[tt], 0, 0, 0);
                acc[tt] = __builtin_amdgcn_mfma_f32_16x16x32_f16(ahi[kc], blo[tt][kc], acc[tt], 0, 0, 0);
                acc[tt] = __builtin_amdgcn_mfma_f32_16x16x32_f16(alo[kc], bhi[tt][kc], acc[tt], 0, 0, 0);
            }
        if (k >= 3) {
            if (tid == 0) {
                while (atomicAdd(cons, 0) < k - 2) __builtin_amdgcn_s_sleep(2);
            }
            __syncthreads();
        }
        float* dst = PreRing + (k % 3) * 8192;
#pragma unroll
        for (int tt = 0; tt < 4; ++tt)
#pragma unroll
            for (int reg = 0; reg < 4; ++reg)
                dst[(quad * 4 + reg) * 512 + tt * 128 + 16 * w + sub] = acc[tt][reg];
        __syncthreads();
        if (tid == 0) {
            __threadfence();
            atomicExch(&fP[k], 1);
        }
    }
    __builtin_amdgcn_s_setprio(0);
}

// ---------------------------------------------------------------------------
// Rec block (layers 1,2): rec weights resident forever.
// ---------------------------------------------------------------------------
__device__ __forceinline__ void rec_body(LstmSh& sh, int b, int layer,
    const float* __restrict__ Whh,
    const float* __restrict__ PreRing, int* __restrict__ fP,
    int* __restrict__ cons,
    float* __restrict__ Hout, int* __restrict__ fHout,  // layer1 only
    float* __restrict__ xl_out)                         // layer2 only
{
    int tid = threadIdx.x;
    int w = tid >> 6, lane = tid & 63, quad = lane >> 4, sub = lane & 15;
    int hu = 16 * w + sub, c4 = quad;
    const float* WhhL = Whh + layer * 65536;

    __builtin_amdgcn_s_setprio(1);
    float4v wgt[4][8];
#pragma unroll
    for (int g = 0; g < 4; ++g) {
        const float4v* p = (const float4v*)(WhhL + (g * 128 + hu) * 128 + c4 * 32);
#pragma unroll
        for (int k = 0; k < 8; ++k) wgt[g][k] = p[k];
    }
    sh.hbuf[0][c4 * 136 + hu] = 0.f;
    float cvar = 0.f;
    __syncthreads();

    for (int k = 0; k < 6; ++k) {
        if (tid == 0) {
            while (atomicAdd(&fP[k], 0) == 0) __builtin_amdgcn_s_sleep(2);
            __threadfence();   // acquire: invalidate L1 (ring slot reuse)
        }
        __syncthreads();
        const float* PreC = PreRing + (k % 3) * 8192;
        for (int tl = 0; tl < 16; ++tl) {
            int t = k * 16 + tl;
            int rb = t & 1, wb = rb ^ 1;
            float pre[4];
#pragma unroll
            for (int g = 0; g < 4; ++g)
                pre[g] = PreC[tl * 512 + g * 128 + hu];
            const float4v* hc = (const float4v*)(&sh.hbuf[rb][c4 * 168]);
            float4v p4[4];
#pragma unroll
            for (int g = 0; g < 4; ++g) { float4v z = {0.f,0.f,0.f,0.f}; p4[g] = z; }
#pragma unroll
            for (int kk = 0; kk < 8; ++kk) {
                float4v hv = hc[kk];
#pragma unroll
                for (int g = 0; g < 4; ++g) p4[g] += wgt[g][kk] * hv;
            }
            float p[4];
#pragma unroll
            for (int g = 0; g < 4; ++g) {
                float s = p4[g].x + p4[g].y + p4[g].z + p4[g].w;
                s += __shfl_xor(s, 16, 64);
                s += __shfl_xor(s, 32, 64);
                p[g] = s + pre[g];
            }
            float c = sigm(p[1]) * cvar + sigm(p[0]) * tanhp(p[2]);
            cvar = c;
            float h = sigm(p[3]) * tanhp(c);
            sh.hbuf[wb][c4 * 136 + hu] = h;
            if (c4 == 0) {
                if (layer == 1) sh.stage[0][tl * 132 + hu] = h;
                else if (t == 95) xl_out[b * 128 + hu] = h;
            }
            __syncthreads();
        }
        if (tid == 0) atomicExch(cons, k + 1);
        if (layer == 1) {
            float* outp = Hout + k * 2048;
#pragma unroll
            for (int u = 0; u < 4; ++u) {
                int e = tid * 4 + u;
                atomicExch(&outp[e], sh.stage[0][(e >> 7) * 132 + (e & 127)]);
            }
            __syncthreads();
            if (tid == 0) atomicExch(&fHout[k], 1);
        }
    }
    __builtin_amdgcn_s_setprio(0);
}

// ---------------------------------------------------------------------------
// GAT body: r11 VERBATIM.
// ---------------------------------------------------------------------------
__device__ __forceinline__ void gat_body(GatSh& s, int m,
    const float* __restrict__ x, const float* __restrict__ adj,
    const float* __restrict__ W_emb, const float* __restrict__ b_emb,
    const float* __restrict__ W1, const float* __restrict__ a1,
    const float* __restrict__ W2, const float* __restrict__ a2,
    float* __restrict__ attn_out, float* __restrict__ xg)
{
    int tid = threadIdx.x;

    if (tid < 128) s.xv[tid] = x[m * 128 + tid];
#pragma unroll
    for (int base = 0; base < 16384; base += 512) {
        int idx = base + tid;
        unsigned long long msk = __ballot(adj[idx] > 0.f);
        if ((tid & 63) == 0) s.adjm[idx >> 6] = msk;
    }
    if (tid < 32) {
        float su = 0.f, sv = 0.f;
        for (int kk = 0; kk < 32; ++kk) {
            float w1v = W1[kk * 32 + tid];
            su += W_emb[kk] * w1v;
            sv += b_emb[kk] * w1v;
        }
        s.u1[tid] = su; s.v1[tid] = sv;
    }
    __syncthreads();
    if (tid < 4) {
        const float* av = a1 + ((tid >= 2) ? 32 : 0);
        const float* uv = (tid & 1) ? s.v1 : s.u1;
        float sum = 0.f;
        for (int f = 0; f < 32; ++f) sum += uv[f] * av[f];
        s.coef[tid] = sum;
    }
    __syncthreads();
    float cL = s.coef[0], dL = s.coef[1], cR = s.coef[2], dR = s.coef[3];

    {
        int i = tid & 127, q = tid >> 7;
        unsigned int ms = (unsigned int)(s.adjm[(i << 1) | (q >> 1)] >> ((q & 1) * 32));
        float Li = s.xv[i] * cL + dL;
        float den = 0.f, wsum = 0.f;
        int j0 = q * 32;
#pragma unroll
        for (int jj = 0; jj < 32; ++jj) {
            if ((ms >> jj) & 1) {
                float xj = s.xv[j0 + jj];
                float e = Li + xj * cR + dR;
                e = e > 0.f ? e : 0.2f * e;
                float p = fast_exp(e);
                den += p; wsum += p * xj;
            }
        }
        s.d_h[q][i] = den; s.s_h[q][i] = wsum;
    }
    __syncthreads();
    if (tid < 128) {
        float den = 0.f, wsum = 0.f;
#pragma unroll
        for (int q = 0; q < 4; ++q) { den += s.d_h[q][tid]; wsum += s.s_h[q][tid]; }
        s.s1v[tid] = wsum / den;
    }
    __syncthreads();
#pragma unroll
    for (int e0 = 0; e0 < 4096; e0 += 512) {
        int e = e0 + tid;
        int i = e >> 5, f = e & 31;
        float v = s.s1v[i] * s.u1[f] + s.v1[f];
        s.h2s[i * 33 + f] = v > 0.f ? v : fast_exp(v) - 1.f;
    }
    __syncthreads();
    {
        int i = tid >> 2, g0 = (tid & 3) * 4;
        float accv[4] = {0.f, 0.f, 0.f, 0.f};
        for (int f = 0; f < 32; ++f) {
            float hv = s.h2s[i * 33 + f];
#pragma unroll
            for (int g = 0; g < 4; ++g) accv[g] += hv * W2[f * 16 + g0 + g];
        }
#pragma unroll
        for (int g = 0; g < 4; ++g) s.wh2[i * 17 + g0 + g] = accv[g];
    }
    __syncthreads();
    if (tid < 256) {
        int i = tid & 127, which = tid >> 7;
        const float* aa = a2 + which * 16;
        float sum = 0.f;
#pragma unroll
        for (int g = 0; g < 16; ++g) sum += s.wh2[i * 17 + g] * aa[g];
        (which ? s.Rv : s.Lv)[i] = sum;
    }
    __syncthreads();
    {
        int i = tid & 127, q = tid >> 7;
        unsigned int ms = (unsigned int)(s.adjm[(i << 1) | (q >> 1)] >> ((q & 1) * 32));
        float Li = s.Lv[i];
        float den = 0.f;
        int j0 = q * 32;
#pragma unroll
        for (int jj = 0; jj < 32; ++jj) {
            if ((ms >> jj) & 1) {
                float e = Li + s.Rv[j0 + jj];
                e = e > 0.f ? e : 0.2f * e;
                den += fast_exp(e);
            }
        }
        s.d_h[q][i] = den;
    }
    __syncthreads();
    if (tid < 128) {
        float den = 0.f;
#pragma unroll
        for (int q = 0; q < 4; ++q) den += s.d_h[q][tid];
        s.rd2[tid] = 1.0f / den;
    }
    __syncthreads();

    float* aout = attn_out + (size_t)m * 16384;
#pragma unroll
    for (int k = 0; k < 8; ++k) {
        int e0 = k * 2048 + tid * 4;
        int i = e0 >> 7, j0 = e0 & 127;
        unsigned int bits = (unsigned int)(s.adjm[(i << 1) | (j0 >> 6)] >> (j0 & 63)) & 0xFu;
        float Li = s.Lv[i], ri = s.rd2[i];
        float4v p;
#pragma unroll
        for (int u = 0; u < 4; ++u) {
            float pv = 0.f;
            if ((bits >> u) & 1) {
                float e = Li + s.Rv[j0 + u];
                e = e > 0.f ? e : 0.2f * e;
                pv = fast_exp(e) * ri;
            }
            p[u] = pv;
        }
        *(float4v*)(aout + e0) = p;
    }

    if (m % 96 == 95) {
        int b = m / 96;
        int i = tid >> 2, g0 = (tid & 3) * 4;
        unsigned long long mA = s.adjm[i << 1], mB = s.adjm[(i << 1) | 1];
        float Li = s.Lv[i], ri = s.rd2[i];
        float accv[4] = {0.f, 0.f, 0.f, 0.f};
        for (int j = 0; j < 128; ++j) {
            unsigned long long mm = (j < 64) ? mA : mB;
            if ((mm >> (j & 63)) & 1) {
                float e = Li + s.Rv[j];
                e = e > 0.f ? e : 0.2f * e;
                float p = fast_exp(e) * ri;
#pragma unroll
                for (int g = 0; g < 4; ++g) accv[g] += p * s.wh2[j * 17 + g0 + g];
            }
        }
#pragma unroll
        for (int g = 0; g < 4; ++g) xg[b * 2048 + i * 16 + g0 + g] = accv[g];
    }
}

// ---------------------------------------------------------------------------
// Fused kernel. Flag layout per batch (stride 32 ints):
//   [0..5] fH0   [8..13] fP1   [14] cons1
//   [16..21] fH1 [24..29] fP2  [30] cons2
// Head counter lives at flags[512].
// ---------------------------------------------------------------------------
__global__ __launch_bounds__(512, 2) void fused_kernel(
    const float* __restrict__ x, const float* __restrict__ adj,
    const float* __restrict__ W_emb, const float* __restrict__ b_emb,
    const float* __restrict__ W1, const float* __restrict__ a1,
    const float* __restrict__ W2, const float* __restrict__ a2,
    const float* __restrict__ Wih, const float* __restrict__ Whh,
    const float* __restrict__ bih, const float* __restrict__ bhh,
    float* __restrict__ Pre0, float* __restrict__ Pre1, float* __restrict__ Pre2,
    float* __restrict__ H0, float* __restrict__ H1,
    int* __restrict__ flags, float* __restrict__ xl_out,
    float* __restrict__ attn_out, float* __restrict__ xg)
{
    __shared__ ShU sh;
    int bb = blockIdx.x;
    if (bb < 80) {
        int grp = bb >> 4, b = bb & 15;
        int* F = flags + b * 32;
        if (grp == 0) {
            l0_body(sh.l, b, x, Wih, Whh, bih, bhh,
                    Pre0 + b * 49152, H0 + b * 12288, F + 0);
        } else if (grp == 1) {
            proj_body(sh.l, 1, Wih, bih, bhh,
                      H0 + b * 12288, F + 0, Pre1 + b * 24576, F + 8, F + 14);
        } else if (grp == 2) {
            rec_body(sh.l, b, 1, Whh,
                     Pre1 + b * 24576, F + 8, F + 14,
                     H1 + b * 12288, F + 16, nullptr);
        } else if (grp == 3) {
            proj_body(sh.l, 2, Wih, bih, bhh,
                      H1 + b * 12288, F + 16, Pre2 + b * 24576, F + 24, F + 30);
        } else {
            rec_body(sh.l, b, 2, Whh,
                     Pre2 + b * 24576, F + 24, F + 30,
                     nullptr, nullptr, xl_out);
        }
    } else {
        gat_body(sh.g, bb - 80, x, adj, W_emb, b_emb, W1, a1, W2, a2, attn_out, xg);
    }
}

// ---------------------------------------------------------------------------
// Merged heads: 48 blocks compute partials; last block (atomic counter)
// runs the final stage. threadfence release/acquire (r14/r15-proven).
// ---------------------------------------------------------------------------
__global__ __launch_bounds__(256) void head_kernel(
    const float* __restrict__ xl, const float* __restrict__ xg,
    const float* __restrict__ W1, float* __restrict__ hp,
    int* __restrict__ counter,
    const float* __restrict__ b1,
    const float* __restrict__ W2, const float* __restrict__ b2,
    const float* __restrict__ W3d, const float* __restrict__ b3d,
    const float* __restrict__ W3r, const float* __restrict__ b3r,
    const float* __restrict__ W3v, const float* __restrict__ b3v,
    float* __restrict__ out)
{
    __shared__ float h1s[3 * 16 * 64];
    __shared__ float h2s[3 * 16 * 32];
    __shared__ int isLast;
    int tid = threadIdx.x;
    {
        int k = blockIdx.x >> 4, chunk = blockIdx.x & 15;
        int d = tid & 63, bg = tid >> 6;
        float acc[4] = {0.f, 0.f, 0.f, 0.f};
        int c0 = chunk * 136;
        for (int cc = c0; cc < c0 + 136; ++cc) {
            float wv = W1[(k * 2176 + cc) * 64 + d];
#pragma unroll
            for (int u = 0; u < 4; ++u) {
                int b = bg * 4 + u;
                float cv = (cc < 128) ? xl[b * 128 + cc] : xg[b * 2048 + cc - 128];
                acc[u] += wv * cv;
            }
        }
#pragma unroll
        for (int u = 0; u < 4; ++u)
            hp[(((k * 16 + chunk) * 16) + bg * 4 + u) * 64 + d] = acc[u];
    }
    __threadfence();   // release: hp visible device-wide
    if (tid == 0) {
        int old = atomicAdd(counter, 1);
        isLast = (old == 47);
    }
    __syncthreads();
    if (!isLast) return;
    __threadfence();   // acquire (other blocks' hp lines are L1-cold anyway)

    for (int o = tid; o < 3072; o += 256) {
        int k = o >> 10, rem = o & 1023, b = rem >> 6, d = rem & 63;
        float s = b1[k * 64 + d];
        for (int ch = 0; ch < 16; ++ch)
            s += hp[(((k * 16 + ch) * 16) + b) * 64 + d];
        h1s[o] = fmaxf(s, 0.f);
    }
    __syncthreads();
    for (int o = tid; o < 1536; o += 256) {
        int k = o >> 9, rem = o & 511, b = rem >> 5, e = rem & 31;
        float s = b2[k * 32 + e];
        for (int dd = 0; dd < 64; ++dd)
            s += h1s[(k * 16 + b) * 64 + dd] * W2[(k * 64 + dd) * 32 + e];
        h2s[o] = fmaxf(s, 0.f);
    }
    __syncthreads();
    if (tid < 64) {
        if (tid < 16) {
            int b = tid; float s = b3d[0];
            for (int e = 0; e < 32; ++e) s += h2s[b * 32 + e] * W3d[e];
            out[b] = s;
        } else if (tid < 32) {
            int b = tid - 16; float s = b3r[0];
            for (int e = 0; e < 32; ++e) s += h2s[(16 + b) * 32 + e] * W3r[e];
            out[16 + b] = s;
        } else {
            int b = (tid - 32) >> 1, j = tid & 1; float s = b3v[j];
            for (int e = 0; e < 32; ++e) s += h2s[(32 + b) * 32 + e] * W3v[e * 2 + j];
            out[32 + b * 2 + j] = s;
        }
    }
}

// ---------------------------------------------------------------------------
extern "C" void kernel_launch(void* const* d_in, const int* in_sizes, int n_in,
                              void* d_out, int out_size, void* d_ws, size_t ws_size,
                              hipStream_t stream)
{
    const float* x     = (const float*)d_in[0];
    const float* adj   = (const float*)d_in[1];
    const float* W_emb = (const float*)d_in[2];
    const float* b_emb = (const float*)d_in[3];
    const float* W1    = (const float*)d_in[4];
    const float* a1    = (const float*)d_in[5];
    const float* W2    = (const float*)d_in[6];
    const float* a2    = (const float*)d_in[7];
    const float* Wih   = (const float*)d_in[8];
    const float* Whh   = (const float*)d_in[9];
    const float* bih   = (const float*)d_in[10];
    const float* bhh   = (const float*)d_in[11];
    const float* hW1   = (const float*)d_in[12];
    const float* hb1   = (const float*)d_in[13];
    const float* hW2   = (const float*)d_in[14];
    const float* hb2   = (const float*)d_in[15];
    const float* W3d   = (const float*)d_in[16];
    const float* b3d   = (const float*)d_in[17];
    const float* W3r   = (const float*)d_in[18];
    const float* b3r   = (const float*)d_in[19];
    const float* W3v   = (const float*)d_in[20];
    const float* b3v   = (const float*)d_in[21];

    float* out = (float*)d_out;
    float* wsf = (float*)d_ws;
    float* XG    = wsf;                    // 32768
    float* XL    = wsf + 32768;            // 2048
    float* HP    = wsf + 34816;            // 49152 -> 83968
    int*   FLAGS = (int*)(wsf + 83968);    // 16*32 flags + head counter @512
    float* PRE0  = wsf + 84992;            // 16*49152 -> 871424
    float* PRE1  = wsf + 871424;           // 16*3*8192 -> 1264640
    float* PRE2  = wsf + 1264640;          // -> 1657856
    float* H0    = wsf + 1657856;          // 16*12288 -> 1854464
    float* H1    = wsf + 1854464;          // -> 2051072 (8.2 MB)

    hipMemsetAsync(FLAGS, 0, (16 * 32 + 8) * sizeof(int), stream);
    fused_kernel<<<1616, 512, 0, stream>>>(
        x, adj, W_emb, b_emb, W1, a1, W2, a2,
        Wih, Whh, bih, bhh, PRE0, PRE1, PRE2, H0, H1, FLAGS, XL, out + 64, XG);
    head_kernel<<<48, 256, 0, stream>>>(
        XL, XG, hW1, HP, FLAGS + 512,
        hb1, hW2, hb2, W3d, b3d, W3r, b3r, W3v, b3v, out);
}